// Round 9
// baseline (1086.296 us; speedup 1.0000x reference)
//
#include <hip/hip_runtime.h>
#include <cstddef>

#define BB   256    // batch (GEMM1 M)
#define UU   8      // in_units
#define ISZ  1152   // in_size
#define JJ   10     // out_units
#define DD   16     // out_size
#define JD   (JJ*DD)      // 160
#define K1   (UU*ISZ)     // 9216
#define KS   8            // split-K for sgemm
#define KCH  (K1/KS)      // 1152
#define GRID 512

typedef short v8s __attribute__((ext_vector_type(8)));   // 8 bf16 in 4 VGPRs
typedef float f4v __attribute__((ext_vector_type(4)));   // mfma accumulator

__device__ __forceinline__ unsigned short f2bf(float f) {
    unsigned int u = __float_as_uint(f);
    unsigned int r = (u + 0x7fffu + ((u >> 16) & 1u)) >> 16;   // RNE
    return (unsigned short)r;
}
__device__ __forceinline__ float bf2f(unsigned short h) {
    return __uint_as_float(((unsigned int)h) << 16);
}
__device__ __forceinline__ float aload(const float* p) {
    return __hip_atomic_load(p, __ATOMIC_RELAXED, __HIP_MEMORY_SCOPE_AGENT);
}

// one-shot grid barrier: fresh zeroed counter per event (no reset/ABA).
// release fetch_add = L2 writeback of prior stores; acquire load = invalidate.
__device__ __forceinline__ void gbar(int* bar, int idx) {
    __syncthreads();
    if (threadIdx.x == 0) {
        __hip_atomic_fetch_add(&bar[idx], 1, __ATOMIC_RELEASE, __HIP_MEMORY_SCOPE_AGENT);
        while (__hip_atomic_load(&bar[idx], __ATOMIC_ACQUIRE, __HIP_MEMORY_SCOPE_AGENT) < GRID)
            __builtin_amdgcn_s_sleep(8);
    }
    __syncthreads();
}

__global__ __launch_bounds__(256, 2) void capsule_persist(
        const float* __restrict__ x, const float* __restrict__ W,
        float* __restrict__ v_out, int* bar,
        float* __restrict__ b_ij, float* __restrict__ s_part,
        unsigned short* __restrict__ xbh, unsigned short* __restrict__ xbl,
        unsigned short* __restrict__ xth, unsigned short* __restrict__ xtl,
        unsigned short* __restrict__ bth, unsigned short* __restrict__ btl,
        unsigned short* __restrict__ vth, unsigned short* __restrict__ vtl) {
    int bid = blockIdx.x;
    int t = threadIdx.x;
    int lane = t & 63, wv = t >> 6;
    int bi = 0;

    __shared__ float tile[64][65];
    __shared__ float redm[4], reds[4];
    __shared__ float sm[JD];

    // ---- P0: prep x -> bf16-split (row-major + transposed); b_ij = 1 ----
    if (bid < 45) b_ij[bid * 256 + t] = 1.0f;
    for (int job = bid; job < 576; job += GRID) {
        int kt = job % 144, bt = job / 144;
        int k0 = kt * 64, b0 = bt * 64;
#pragma unroll
        for (int r = 0; r < 16; ++r) {
            int br = wv * 16 + r;
            float v = x[(size_t)(b0 + br) * K1 + k0 + lane];
            tile[br][lane] = v;
            unsigned short h = f2bf(v);
            size_t o = (size_t)(b0 + br) * K1 + k0 + lane;
            xbh[o] = h; xbl[o] = f2bf(v - bf2f(h));
        }
        __syncthreads();
#pragma unroll
        for (int r = 0; r < 16; ++r) {
            int kr = wv * 16 + r;
            float v = tile[lane][kr];
            unsigned short h = f2bf(v);
            size_t o = (size_t)(k0 + kr) * BB + b0 + lane;
            xth[o] = h; xtl[o] = f2bf(v - bf2f(h));
        }
        __syncthreads();
    }
    gbar(bar, bi++);

    for (int it = 0; it < 3; ++it) {
        // ---- P1: B^T[(j,d)][(u,i)] = bf16split(c[i,j]*W), fused softmax ----
        if (bid < JD) {
            int jd = bid, j = jd >> 4;
            float m = 0.f, inv = 1.0f / 1152.0f;
            if (it != 0) {
                const float* bp = b_ij + (size_t)j * ISZ;
                m = -1e30f;
                for (int k = t; k < ISZ; k += 256) m = fmaxf(m, aload(bp + k));
#pragma unroll
                for (int off = 32; off; off >>= 1) m = fmaxf(m, __shfl_down(m, off, 64));
                if (lane == 0) redm[wv] = m;
                __syncthreads();
                m = fmaxf(fmaxf(redm[0], redm[1]), fmaxf(redm[2], redm[3]));
                float ss = 0.f;
                for (int k = t; k < ISZ; k += 256) ss += __expf(aload(bp + k) - m);
#pragma unroll
                for (int off = 32; off; off >>= 1) ss += __shfl_down(ss, off, 64);
                if (lane == 0) reds[wv] = ss;
                __syncthreads();
                inv = 1.f / (reds[0] + reds[1] + reds[2] + reds[3]);
            }
            for (int i = t; i < ISZ; i += 256) {
                float ci = (it == 0) ? inv
                         : __expf(aload(b_ij + (size_t)j * ISZ + i) - m) * inv;
                const float* Wp = W + (size_t)i * (JD * UU) + jd * UU;
#pragma unroll
                for (int u = 0; u < 8; ++u) {
                    float val = ci * Wp[u];
                    unsigned short h = f2bf(val);
                    size_t o = (size_t)jd * K1 + (size_t)u * ISZ + i;
                    bth[o] = h; btl[o] = f2bf(val - bf2f(h));
                }
            }
        }
        gbar(bar, bi++);

        // ---- P2: split-K GEMM  s_part[ks][b][jd] = x @ B  (320 jobs) ----
        if (bid < 320) {
            int bx = bid & 3, nt = (bid >> 2) % 10, ks = bid / 40;
            int mt = bx * 4 + wv;
            int m0 = mt * 16, n0 = nt * 16;
            int col = lane & 15, q = lane >> 4;
            size_t aoff = (size_t)(m0 + col) * K1 + (size_t)ks * KCH + q * 8;
            size_t boff = (size_t)(n0 + col) * K1 + (size_t)ks * KCH + q * 8;
            f4v acc = {0.f, 0.f, 0.f, 0.f};
#pragma unroll
            for (int s = 0; s < KCH / 32; ++s) {
                v8s ah = *(const v8s*)(xbh + aoff);
                v8s al = *(const v8s*)(xbl + aoff);
                v8s bh = *(const v8s*)(bth + boff);
                v8s bl = *(const v8s*)(btl + boff);
                acc = __builtin_amdgcn_mfma_f32_16x16x32_bf16(ah, bh, acc, 0, 0, 0);
                acc = __builtin_amdgcn_mfma_f32_16x16x32_bf16(ah, bl, acc, 0, 0, 0);
                acc = __builtin_amdgcn_mfma_f32_16x16x32_bf16(al, bh, acc, 0, 0, 0);
                aoff += 32; boff += 32;
            }
#pragma unroll
            for (int r = 0; r < 4; ++r)
                s_part[((size_t)ks * BB + m0 + q * 4 + r) * JD + n0 + col] = acc[r];
        }
        gbar(bar, bi++);

        // ---- P3: reduce split-K + squash; v -> d_out, vT bf16-split ----
        if (bid < BB) {
            int b = bid;
            float s = 0.f;
            if (t < JD) {
#pragma unroll
                for (int ks = 0; ks < KS; ++ks) s += s_part[((size_t)ks * BB + b) * JD + t];
                sm[t] = s;
            }
            __syncthreads();
            if (t < JD) {
                int d = t & 15;
                float msq = 0.f;
#pragma unroll
                for (int j = 0; j < JJ; ++j) { float xx = sm[j * DD + d]; msq += xx * xx; }
                float val = msq / (1.f + msq) * s * rsqrtf(msq);
                v_out[(size_t)b * JD + t] = val;
                unsigned short h = f2bf(val);
                vth[(size_t)t * BB + b] = h;
                vtl[(size_t)t * BB + b] = f2bf(val - bf2f(h));
            }
            __syncthreads();
        }

        if (it < 2) {
            gbar(bar, bi++);
            // ---- P4: mGEMM (vT @ x, K=256) + fused agreement epilogue ----
            for (int job = bid; job < 1440; job += GRID) {
                int wj = job * 4 + wv;
                int mt = wj / 576, nt = wj % 576;
                int m0 = mt * 16, n0 = nt * 16;
                int col = lane & 15, q = lane >> 4;
                size_t aoff = (size_t)(m0 + col) * BB + q * 8;
                size_t boff = (size_t)(n0 + col) * BB + q * 8;
                f4v acc = {0.f, 0.f, 0.f, 0.f};
#pragma unroll
                for (int s = 0; s < BB / 32; ++s) {
                    v8s ah = *(const v8s*)(vth + aoff);
                    v8s al = *(const v8s*)(vtl + aoff);
                    v8s bh = *(const v8s*)(xth + boff);
                    v8s bl = *(const v8s*)(xtl + boff);
                    acc = __builtin_amdgcn_mfma_f32_16x16x32_bf16(ah, bh, acc, 0, 0, 0);
                    acc = __builtin_amdgcn_mfma_f32_16x16x32_bf16(ah, bl, acc, 0, 0, 0);
                    acc = __builtin_amdgcn_mfma_f32_16x16x32_bf16(al, bh, acc, 0, 0, 0);
                    aoff += 32; boff += 32;
                }
                int u = nt / 72;
                int i = (nt % 72) * 16 + col;
                const float* Wp = W + (size_t)i * (JD * UU) + mt * (DD * UU) + q * 32 + u;
                float p = Wp[0] * acc[0] + Wp[8] * acc[1] + Wp[16] * acc[2] + Wp[24] * acc[3];
                p += __shfl_xor(p, 16, 64);
                p += __shfl_xor(p, 32, 64);
                if (q == 0) atomicAdd(&b_ij[(size_t)mt * ISZ + i], p * (1.0f / 256.0f));
            }
            gbar(bar, bi++);
        }
    }
}

extern "C" void kernel_launch(void* const* d_in, const int* in_sizes, int n_in,
                              void* d_out, int out_size, void* d_ws, size_t ws_size,
                              hipStream_t stream) {
    const float* x = (const float*)d_in[0];   // (256, 8, 1152)
    const float* W = (const float*)d_in[1];   // (1, 1152, 10, 16, 8)
    float* v_out = (float*)d_out;             // (256, 10, 16, 1)

    int*   bar    = (int*)d_ws;                            // 256 ints (use 11)
    float* b_ij   = (float*)d_ws + 256;                    // 11,520 f
    float* s_part = b_ij + ISZ * JJ;                       // 8*256*160 = 327,680 f
    unsigned short* xbh = (unsigned short*)(s_part + (size_t)KS * BB * JD);
    unsigned short* xbl = xbh + (size_t)BB * K1;
    unsigned short* xth = xbl + (size_t)BB * K1;
    unsigned short* xtl = xth + (size_t)BB * K1;
    unsigned short* bth = xtl + (size_t)BB * K1;
    unsigned short* btl = bth + (size_t)JD * K1;
    unsigned short* vth = btl + (size_t)JD * K1;
    unsigned short* vtl = vth + (size_t)JD * BB;

    hipMemsetAsync(bar, 0, 256 * sizeof(int), stream);   // zero barrier counters
    hipLaunchKernelGGL(capsule_persist, dim3(GRID), dim3(256), 0, stream,
                       x, W, v_out, bar, b_ij, s_part,
                       xbh, xbl, xth, xtl, bth, btl, vth, vtl);
}

// Round 10
// 293.000 us; speedup vs baseline: 3.7075x; 3.7075x over previous
//
#include <hip/hip_runtime.h>
#include <cstddef>

#define BB   256    // batch = GEMM1 M
#define UU   8      // in_units
#define ISZ  1152   // in_size
#define JJ   10     // out_units
#define DD   16     // out_size
#define JD   (JJ*DD)      // 160
#define K1   (UU*ISZ)     // 9216 ; sgemm k-order: k = i*8+u
#define KS   2            // split-K halves in sgemm (i<576 / i>=576)

typedef short v8s __attribute__((ext_vector_type(8)));   // 8 bf16 in 4 VGPRs
typedef float f4v __attribute__((ext_vector_type(4)));   // mfma accumulator
typedef unsigned short ush;

__device__ __forceinline__ ush f2bf(float f) {
    unsigned int u = __float_as_uint(f);
    unsigned int r = (u + 0x7fffu + ((u >> 16) & 1u)) >> 16;   // RNE
    return (ush)r;
}
__device__ __forceinline__ float bf2f(ush h) {
    return __uint_as_float(((unsigned int)h) << 16);
}

// ---------------- prep: x[b,u,i] -> xs[i][b*8+u] (split) + xt[u*1152+i][b] (split); b_ij=1 ----
__global__ void prep_kernel(const float* __restrict__ x,
                            ush* __restrict__ xsh, ush* __restrict__ xsl,
                            ush* __restrict__ xth, ush* __restrict__ xtl,
                            float* __restrict__ b_ij) {
    __shared__ float buf[32][8][65];
    int it = blockIdx.x;            // 18 tiles of 64 i
    int bt = blockIdx.y;            // 8 tiles of 32 b
    int i0 = it * 64, b0 = bt * 32;
    int t = threadIdx.x, lane = t & 63, wv = t >> 6;

    int flat = bt * 18 + it;
    if (flat < 45) b_ij[flat * 256 + t] = 1.0f;   // 45*256 = 11520

    for (int rep = 0; rep < 64; ++rep) {
        int row = rep * 4 + wv;     // 0..255 = (bl,u)
        int bl = row >> 3, u = row & 7;
        buf[bl][u][lane] = x[(size_t)(b0 + bl) * K1 + (size_t)u * ISZ + i0 + lane];
    }
    __syncthreads();
    {   // xs[i][b*8+u]: per il, 256 consecutive shorts
        int bl = t >> 3, u = t & 7;
        for (int il = 0; il < 64; ++il) {
            float v = buf[bl][u][il];
            ush h = f2bf(v);
            size_t o = (size_t)(i0 + il) * 2048 + (size_t)(b0 + bl) * 8 + u;
            xsh[o] = h; xsl[o] = f2bf(v - bf2f(h));
        }
    }
    {   // xt[u*1152+i][b]: groups of 32 consecutive b
        int g = t >> 5, bl = t & 31;
        for (int pass = 0; pass < 64; ++pass) {
            int cu = pass * 8 + g;
            int u = cu >> 6, il = cu & 63;
            float v = buf[bl][u][il];
            ush h = f2bf(v);
            size_t o = (size_t)(u * ISZ + i0 + il) * BB + b0 + bl;
            xth[o] = h; xtl[o] = f2bf(v - bf2f(h));
        }
    }
}

// ---------------- sgemm_fused: s_part[ks][b][jd] = x @ (c.W), B built in LDS ----------------
// grid (4, 10, KS), block 256 = 4 waves (m-tiles). k = i*8+u.
__global__ __launch_bounds__(256, 2) void sgemm_fused(
        const ush* __restrict__ xsh, const ush* __restrict__ xsl,
        const float* __restrict__ W, const float* __restrict__ b_ij,
        float* __restrict__ s_part, int first) {
    int bx = blockIdx.x;            // m-group
    int nt = blockIdx.y;            // j
    int ks = blockIdx.z;            // i-half
    int t = threadIdx.x, lane = t & 63, wv = t >> 6;
    int col = lane & 15, q = lane >> 4;
    int I0 = ks * 576;

    __shared__ ush bhl[16][584];    // B^T hi: [d][k_local], padded (16B-aligned rows)
    __shared__ ush bll[16][584];    // B^T lo
    __shared__ float c_lds[576];
    __shared__ float redm[4], reds[4];

    if (first) {
        for (int idx = t; idx < 576; idx += 256) c_lds[idx] = 1.0f / 1152.0f;
    } else {
        const float* bp = b_ij + (size_t)nt * ISZ;
        float m = -1e30f;
        for (int k = t; k < ISZ; k += 256) m = fmaxf(m, bp[k]);
#pragma unroll
        for (int off = 32; off; off >>= 1) m = fmaxf(m, __shfl_down(m, off, 64));
        if (lane == 0) redm[wv] = m;
        __syncthreads();
        m = fmaxf(fmaxf(redm[0], redm[1]), fmaxf(redm[2], redm[3]));
        float ss = 0.f;
        for (int k = t; k < ISZ; k += 256) ss += __expf(bp[k] - m);
#pragma unroll
        for (int off = 32; off; off >>= 1) ss += __shfl_down(ss, off, 64);
        if (lane == 0) reds[wv] = ss;
        __syncthreads();
        float inv = 1.f / (reds[0] + reds[1] + reds[2] + reds[3]);
        for (int idx = t; idx < 576; idx += 256)
            c_lds[idx] = __expf(bp[I0 + idx] - m) * inv;
    }

    int mt = bx * 4 + wv, m0 = mt * 16;
    f4v acc = {0.f, 0.f, 0.f, 0.f};

    for (int sc = 0; sc < 8; ++sc) {        // 8 sub-chunks of 72 i (=576 k)
        int ib = sc * 72;
        __syncthreads();                    // c ready / prior GEMM reads done
        for (int p = t; p < 1152; p += 256) {   // 72 i x 16 d
            int ii = p >> 4, d = p & 15;
            const float* wp = W + (size_t)(I0 + ib + ii) * 1280 + nt * 128 + d * 8;
            float4 wa = *(const float4*)wp;
            float4 wb = *(const float4*)(wp + 4);
            float ci = c_lds[ib + ii];
            float vals[8] = { wa.x * ci, wa.y * ci, wa.z * ci, wa.w * ci,
                              wb.x * ci, wb.y * ci, wb.z * ci, wb.w * ci };
            v8s hv, lv;
#pragma unroll
            for (int u = 0; u < 8; ++u) {
                ush h = f2bf(vals[u]);
                hv[u] = (short)h;
                lv[u] = (short)f2bf(vals[u] - bf2f(h));
            }
            *(v8s*)&bhl[d][ii * 8] = hv;
            *(v8s*)&bll[d][ii * 8] = lv;
        }
        __syncthreads();
#pragma unroll
        for (int s = 0; s < 18; ++s) {      // 576 k = 18 mfma k-steps
            int i = I0 + ib + s * 4 + q;
            size_t ao = (size_t)i * 2048 + (size_t)(m0 + col) * 8;
            v8s ah = *(const v8s*)(xsh + ao);
            v8s al = *(const v8s*)(xsl + ao);
            v8s bh = *(const v8s*)&bhl[col][s * 32 + q * 8];
            v8s bl = *(const v8s*)&bll[col][s * 32 + q * 8];
            acc = __builtin_amdgcn_mfma_f32_16x16x32_bf16(ah, bh, acc, 0, 0, 0);
            acc = __builtin_amdgcn_mfma_f32_16x16x32_bf16(ah, bl, acc, 0, 0, 0);
            acc = __builtin_amdgcn_mfma_f32_16x16x32_bf16(al, bh, acc, 0, 0, 0);
        }
    }
    // C/D: col = n (=d), row = q*4+r (= b within tile)  [R7-verified]
#pragma unroll
    for (int r = 0; r < 4; ++r)
        s_part[((size_t)(ks * BB) + m0 + q * 4 + r) * JD + nt * DD + col] = acc[r];
}

// ---------------- mgemm_sq: squash(s_part) -> A in LDS; A @ xT; fused agreement ----------------
// grid (360), block 256: mt = bid/36 (j), 16 n-tiles per block (4/wave). K=256 (b).
__global__ __launch_bounds__(256, 2) void mgemm_sq(
        const ush* __restrict__ xth, const ush* __restrict__ xtl,
        const float* __restrict__ s_part, const float* __restrict__ W,
        float* __restrict__ b_ij) {
    int bid = blockIdx.x;
    int mt = bid / 36, ntg = bid % 36;
    int t = threadIdx.x, lane = t & 63, wv = t >> 6;
    int col = lane & 15, q = lane >> 4;

    __shared__ ush ahl[16][264];    // v hi: [d][b], padded
    __shared__ ush all_[16][264];   // v lo

    {   // build A rows: thread t = b; squash over full s row
        int b = t;
        const float* sp0 = s_part + (size_t)b * JD;
        const float* sp1 = s_part + (size_t)(BB + b) * JD;
        float msq[16], sv[16];
#pragma unroll
        for (int d = 0; d < 16; ++d) { msq[d] = 0.f; sv[d] = 0.f; }
#pragma unroll
        for (int j = 0; j < 10; ++j) {
#pragma unroll
            for (int dv = 0; dv < 4; ++dv) {
                float4 a = *(const float4*)(sp0 + j * 16 + dv * 4);
                float4 c = *(const float4*)(sp1 + j * 16 + dv * 4);
                float s0 = a.x + c.x, s1 = a.y + c.y, s2 = a.z + c.z, s3 = a.w + c.w;
                msq[dv * 4 + 0] += s0 * s0; msq[dv * 4 + 1] += s1 * s1;
                msq[dv * 4 + 2] += s2 * s2; msq[dv * 4 + 3] += s3 * s3;
                if (j == mt) {
                    sv[dv * 4 + 0] = s0; sv[dv * 4 + 1] = s1;
                    sv[dv * 4 + 2] = s2; sv[dv * 4 + 3] = s3;
                }
            }
        }
#pragma unroll
        for (int d = 0; d < 16; ++d) {
            float ms = msq[d];
            float val = ms / (1.f + ms) * sv[d] * rsqrtf(ms);
            ush h = f2bf(val);
            ahl[d][b] = h;
            all_[d][b] = f2bf(val - bf2f(h));
        }
    }
    __syncthreads();

    for (int kk = 0; kk < 4; ++kk) {
        int nt = ntg * 16 + wv * 4 + kk;     // 0..575
        int n0 = nt * 16;
        f4v acc = {0.f, 0.f, 0.f, 0.f};
#pragma unroll
        for (int s = 0; s < 8; ++s) {
            size_t bo = (size_t)(n0 + col) * BB + s * 32 + q * 8;
            v8s bh = *(const v8s*)(xth + bo);
            v8s bl = *(const v8s*)(xtl + bo);
            v8s ah = *(const v8s*)&ahl[col][s * 32 + q * 8];
            v8s al = *(const v8s*)&all_[col][s * 32 + q * 8];
            acc = __builtin_amdgcn_mfma_f32_16x16x32_bf16(ah, bh, acc, 0, 0, 0);
            acc = __builtin_amdgcn_mfma_f32_16x16x32_bf16(ah, bl, acc, 0, 0, 0);
            acc = __builtin_amdgcn_mfma_f32_16x16x32_bf16(al, bh, acc, 0, 0, 0);
        }
        // agreement epilogue [R8-verified]: acc[r] = M[mt*16+q*4+r][k1=n0+col]
        int u = nt / 72;
        int i = (nt % 72) * 16 + col;
        const float* Wp = W + (size_t)i * 1280 + mt * 128 + q * 32 + u;
        float p = Wp[0] * acc[0] + Wp[8] * acc[1] + Wp[16] * acc[2] + Wp[24] * acc[3];
        p += __shfl_xor(p, 16, 64);
        p += __shfl_xor(p, 32, 64);
        if (q == 0) atomicAdd(&b_ij[(size_t)mt * ISZ + i], p * (1.0f / 256.0f));
    }
}

// ---------------- final squash -> d_out ----------------
__global__ void squash_out(const float* __restrict__ s_part, float* __restrict__ v) {
    int b = blockIdx.x, t = threadIdx.x;   // 192, t<160 active
    __shared__ float sm[JD];
    if (t < JD) sm[t] = s_part[(size_t)b * JD + t] + s_part[(size_t)(BB + b) * JD + t];
    __syncthreads();
    if (t < JD) {
        int d = t & 15;
        float msq = 0.f;
#pragma unroll
        for (int j = 0; j < JJ; ++j) { float xx = sm[j * DD + d]; msq += xx * xx; }
        v[(size_t)b * JD + t] = msq / (1.f + msq) * sm[t] * rsqrtf(msq);
    }
}

extern "C" void kernel_launch(void* const* d_in, const int* in_sizes, int n_in,
                              void* d_out, int out_size, void* d_ws, size_t ws_size,
                              hipStream_t stream) {
    const float* x = (const float*)d_in[0];   // (256, 8, 1152)
    const float* W = (const float*)d_in[1];   // (1, 1152, 10, 16, 8)
    float* v_out = (float*)d_out;             // (256, 10, 16, 1)

    float* b_ij   = (float*)d_ws;                          // 11,520 f
    float* s_part = b_ij + ISZ * JJ;                       // 2*256*160 = 81,920 f
    ush* xsh = (ush*)(s_part + (size_t)KS * BB * JD);      // [1152][2048]
    ush* xsl = xsh + (size_t)ISZ * 2048;
    ush* xth = xsl + (size_t)ISZ * 2048;                   // [9216][256]
    ush* xtl = xth + (size_t)K1 * BB;

    hipLaunchKernelGGL(prep_kernel, dim3(18, 8), dim3(256), 0, stream,
                       x, xsh, xsl, xth, xtl, b_ij);
    for (int it = 0; it < 3; ++it) {
        hipLaunchKernelGGL(sgemm_fused, dim3(4, 10, KS), dim3(256), 0, stream,
                           xsh, xsl, W, b_ij, s_part, it == 0 ? 1 : 0);
        if (it < 2) {
            hipLaunchKernelGGL(mgemm_sq, dim3(360), dim3(256), 0, stream,
                               xth, xtl, s_part, W, b_ij);
        }
    }
    hipLaunchKernelGGL(squash_out, dim3(BB), dim3(192), 0, stream, s_part, v_out);
}

// Round 11
// 187.238 us; speedup vs baseline: 5.8017x; 1.5649x over previous
//
#include <hip/hip_runtime.h>
#include <cstddef>

#define BB   256    // batch = GEMM1 M
#define UU   8      // in_units
#define ISZ  1152   // in_size
#define JJ   10     // out_units
#define DD   16     // out_size
#define JD   (JJ*DD)      // 160
#define K1   (UU*ISZ)     // 9216 ; sgemm k-order: k = i*8+u
#define ICH  16           // i per sgemm block
#define NIC  (ISZ/ICH)    // 72  (also split-K part count)
#define NJH  5            // j-pairs

typedef short v8s __attribute__((ext_vector_type(8)));   // 8 bf16 in 4 VGPRs
typedef float f4v __attribute__((ext_vector_type(4)));   // mfma accumulator
typedef unsigned short ush;

__device__ __forceinline__ ush f2bf(float f) {
    unsigned int u = __float_as_uint(f);
    unsigned int r = (u + 0x7fffu + ((u >> 16) & 1u)) >> 16;   // RNE
    return (ush)r;
}
__device__ __forceinline__ float bf2f(ush h) {
    return __uint_as_float(((unsigned int)h) << 16);
}

// ---------------- prep: x[b,u,i] -> xs[i][b*8+u] (split) + xt[u*1152+i][b] (split); b_ij=1 ----
__global__ void prep_kernel(const float* __restrict__ x,
                            ush* __restrict__ xsh, ush* __restrict__ xsl,
                            ush* __restrict__ xth, ush* __restrict__ xtl,
                            float* __restrict__ b_ij) {
    __shared__ float buf[32][8][65];
    int it = blockIdx.x;            // 18 tiles of 64 i
    int bt = blockIdx.y;            // 8 tiles of 32 b
    int i0 = it * 64, b0 = bt * 32;
    int t = threadIdx.x, lane = t & 63, wv = t >> 6;

    int flat = bt * 18 + it;
    if (flat < 45) b_ij[flat * 256 + t] = 1.0f;   // 45*256 = 11520

    for (int rep = 0; rep < 64; ++rep) {
        int row = rep * 4 + wv;     // 0..255 = (bl,u)
        int bl = row >> 3, u = row & 7;
        buf[bl][u][lane] = x[(size_t)(b0 + bl) * K1 + (size_t)u * ISZ + i0 + lane];
    }
    __syncthreads();
    {   // xs[i][b*8+u]
        int bl = t >> 3, u = t & 7;
        for (int il = 0; il < 64; ++il) {
            float v = buf[bl][u][il];
            ush h = f2bf(v);
            size_t o = (size_t)(i0 + il) * 2048 + (size_t)(b0 + bl) * 8 + u;
            xsh[o] = h; xsl[o] = f2bf(v - bf2f(h));
        }
    }
    {   // xt[u*1152+i][b]
        int g = t >> 5, bl = t & 31;
        for (int pass = 0; pass < 64; ++pass) {
            int cu = pass * 8 + g;
            int u = cu >> 6, il = cu & 63;
            float v = buf[bl][u][il];
            ush h = f2bf(v);
            size_t o = (size_t)(u * ISZ + i0 + il) * BB + b0 + bl;
            xth[o] = h; xtl[o] = f2bf(v - bf2f(h));
        }
    }
}

// ---------------- sgemm: s_part[ic][b][jd] for 2 j x 16 i per block ----------------
// grid (NJH, NIC) = (5, 72) = 360 blocks, 256 thr = 4 waves x 4 m-tiles x 2 j.
__global__ __launch_bounds__(256, 2) void sgemm_fused(
        const ush* __restrict__ xsh, const ush* __restrict__ xsl,
        const float* __restrict__ W, const float* __restrict__ b_ij,
        float* __restrict__ s_part, int first) {
    int jh = blockIdx.x, ic = blockIdx.y;
    int j0 = jh * 2, i0 = ic * ICH;
    int t = threadIdx.x, lane = t & 63, wv = t >> 6;
    int col = lane & 15, q = lane >> 4;

    __shared__ __align__(16) ush bh_[2][16][136];   // B^T hi [jj][d][k_local], 16B rows
    __shared__ __align__(16) ush bl_[2][16][136];   // B^T lo
    __shared__ float c_lds[2][ICH];
    __shared__ float redm[4], reds[4];

    if (first) {
        if (t < 2 * ICH) c_lds[t >> 4][t & 15] = 1.0f / 1152.0f;
    } else {
        for (int jj = 0; jj < 2; ++jj) {
            const float* bp = b_ij + (size_t)(j0 + jj) * ISZ;
            float m = -1e30f;
            for (int k = t; k < ISZ; k += 256) m = fmaxf(m, bp[k]);
#pragma unroll
            for (int off = 32; off; off >>= 1) m = fmaxf(m, __shfl_down(m, off, 64));
            if (lane == 0) redm[wv] = m;
            __syncthreads();
            m = fmaxf(fmaxf(redm[0], redm[1]), fmaxf(redm[2], redm[3]));
            float ss = 0.f;
            for (int k = t; k < ISZ; k += 256) ss += __expf(bp[k] - m);
#pragma unroll
            for (int off = 32; off; off >>= 1) ss += __shfl_down(ss, off, 64);
            if (lane == 0) reds[wv] = ss;
            __syncthreads();
            float inv = 1.f / (reds[0] + reds[1] + reds[2] + reds[3]);
            if (t < ICH) c_lds[jj][t] = __expf(bp[i0 + t] - m) * inv;
            __syncthreads();
        }
    }
    __syncthreads();

    // build B tiles: 512 slots = (jj, ii, d), 2 per thread
    for (int slot = t; slot < 512; slot += 256) {
        int jj = slot >> 8, rem = slot & 255, ii = rem >> 4, d = rem & 15;
        const float* wp = W + (size_t)(i0 + ii) * 1280 + (j0 + jj) * 128 + d * 8;
        float4 wa = *(const float4*)wp;
        float4 wb = *(const float4*)(wp + 4);
        float ci = c_lds[jj][ii];
        float vals[8] = { wa.x * ci, wa.y * ci, wa.z * ci, wa.w * ci,
                          wb.x * ci, wb.y * ci, wb.z * ci, wb.w * ci };
        v8s hv, lv;
#pragma unroll
        for (int u = 0; u < 8; ++u) {
            ush h = f2bf(vals[u]);
            hv[u] = (short)h;
            lv[u] = (short)f2bf(vals[u] - bf2f(h));
        }
        *(v8s*)&bh_[jj][d][ii * 8] = hv;
        *(v8s*)&bl_[jj][d][ii * 8] = lv;
    }
    __syncthreads();

    int m_base = wv * 64;
    f4v acc[4][2];
#pragma unroll
    for (int mm = 0; mm < 4; ++mm)
#pragma unroll
        for (int jj = 0; jj < 2; ++jj) acc[mm][jj] = (f4v){0.f, 0.f, 0.f, 0.f};

#pragma unroll
    for (int s = 0; s < 4; ++s) {           // 4 k-steps x 32 k = 128 k (16 i)
        v8s bh0 = *(const v8s*)&bh_[0][col][s * 32 + q * 8];
        v8s bl0 = *(const v8s*)&bl_[0][col][s * 32 + q * 8];
        v8s bh1 = *(const v8s*)&bh_[1][col][s * 32 + q * 8];
        v8s bl1 = *(const v8s*)&bl_[1][col][s * 32 + q * 8];
        size_t abase = (size_t)(i0 + s * 4 + q) * 2048;
#pragma unroll
        for (int mm = 0; mm < 4; ++mm) {
            size_t ao = abase + (size_t)(m_base + mm * 16 + col) * 8;
            v8s ah = *(const v8s*)(xsh + ao);
            v8s al = *(const v8s*)(xsl + ao);
            acc[mm][0] = __builtin_amdgcn_mfma_f32_16x16x32_bf16(ah, bh0, acc[mm][0], 0, 0, 0);
            acc[mm][0] = __builtin_amdgcn_mfma_f32_16x16x32_bf16(ah, bl0, acc[mm][0], 0, 0, 0);
            acc[mm][0] = __builtin_amdgcn_mfma_f32_16x16x32_bf16(al, bh0, acc[mm][0], 0, 0, 0);
            acc[mm][1] = __builtin_amdgcn_mfma_f32_16x16x32_bf16(ah, bh1, acc[mm][1], 0, 0, 0);
            acc[mm][1] = __builtin_amdgcn_mfma_f32_16x16x32_bf16(ah, bl1, acc[mm][1], 0, 0, 0);
            acc[mm][1] = __builtin_amdgcn_mfma_f32_16x16x32_bf16(al, bh1, acc[mm][1], 0, 0, 0);
        }
    }
    // C/D: col = n, row = q*4+r (= b within m-tile)  [R7-verified]
#pragma unroll
    for (int mm = 0; mm < 4; ++mm)
#pragma unroll
        for (int jj = 0; jj < 2; ++jj)
#pragma unroll
            for (int r = 0; r < 4; ++r)
                s_part[((size_t)ic * BB + m_base + mm * 16 + q * 4 + r) * JD
                       + (j0 + jj) * DD + col] = acc[mm][jj][r];
}

// ---------------- reduce split-K + squash; v_out, vT bf16-split ----------------
__global__ void reduce_squash(const float* __restrict__ s_part, float* __restrict__ v,
                              ush* __restrict__ vth, ush* __restrict__ vtl) {
    int b = blockIdx.x, t = threadIdx.x;   // 192, t<160 active
    __shared__ float sm[JD];
    if (t < JD) {
        float s = 0.f;
#pragma unroll 8
        for (int p = 0; p < NIC; ++p) s += s_part[((size_t)p * BB + b) * JD + t];
        sm[t] = s;
    }
    __syncthreads();
    if (t < JD) {
        int d = t & 15;
        float msq = 0.f;
#pragma unroll
        for (int j = 0; j < JJ; ++j) { float xx = sm[j * DD + d]; msq += xx * xx; }
        float val = msq / (1.f + msq) * sm[t] * rsqrtf(msq);
        v[(size_t)b * JD + t] = val;
        ush h = f2bf(val);
        vth[(size_t)t * BB + b] = h;
        vtl[(size_t)t * BB + b] = f2bf(val - bf2f(h));
    }
}

// ---------------- mgemm + agreement epilogue [R7-verified] ----------------
__global__ __launch_bounds__(256) void mgemm_agree(
        const ush* __restrict__ Ah, const ush* __restrict__ Al,
        const ush* __restrict__ Bh, const ush* __restrict__ Bl,
        const float* __restrict__ W, float* __restrict__ b_ij) {
    int w = threadIdx.x >> 6, lane = threadIdx.x & 63;
    int wj = blockIdx.x * 4 + w;        // 5760 wave-jobs
    int mt = wj / 576, nt = wj % 576;
    int m0 = mt * 16, n0 = nt * 16;
    int col = lane & 15, q = lane >> 4;
    size_t aoff = (size_t)(m0 + col) * BB + q * 8;
    size_t boff = (size_t)(n0 + col) * BB + q * 8;
    f4v acc = {0.f, 0.f, 0.f, 0.f};
#pragma unroll
    for (int s = 0; s < BB / 32; ++s) {
        v8s ah = *(const v8s*)(Ah + aoff);
        v8s al = *(const v8s*)(Al + aoff);
        v8s bh = *(const v8s*)(Bh + boff);
        v8s bl = *(const v8s*)(Bl + boff);
        acc = __builtin_amdgcn_mfma_f32_16x16x32_bf16(ah, bh, acc, 0, 0, 0);
        acc = __builtin_amdgcn_mfma_f32_16x16x32_bf16(ah, bl, acc, 0, 0, 0);
        acc = __builtin_amdgcn_mfma_f32_16x16x32_bf16(al, bh, acc, 0, 0, 0);
        aoff += 32; boff += 32;
    }
    int u = nt / 72;
    int i = (nt % 72) * 16 + col;
    const float* Wp = W + (size_t)i * 1280 + mt * 128 + q * 32 + u;
    float p = Wp[0] * acc[0] + Wp[8] * acc[1] + Wp[16] * acc[2] + Wp[24] * acc[3];
    p += __shfl_xor(p, 16, 64);
    p += __shfl_xor(p, 32, 64);
    if (q == 0) atomicAdd(&b_ij[(size_t)mt * ISZ + i], p * (1.0f / 256.0f));
}

extern "C" void kernel_launch(void* const* d_in, const int* in_sizes, int n_in,
                              void* d_out, int out_size, void* d_ws, size_t ws_size,
                              hipStream_t stream) {
    const float* x = (const float*)d_in[0];   // (256, 8, 1152)
    const float* W = (const float*)d_in[1];   // (1, 1152, 10, 16, 8)
    float* v_out = (float*)d_out;             // (256, 10, 16, 1)

    float* b_ij   = (float*)d_ws;                          // 11,520 f
    float* s_part = b_ij + ISZ * JJ;                       // 72*256*160 = 2,949,120 f
    ush* xsh = (ush*)(s_part + (size_t)NIC * BB * JD);     // [1152][2048]
    ush* xsl = xsh + (size_t)ISZ * 2048;
    ush* xth = xsl + (size_t)ISZ * 2048;                   // [9216][256]
    ush* xtl = xth + (size_t)K1 * BB;
    ush* vth = xtl + (size_t)K1 * BB;                      // [160][256]
    ush* vtl = vth + (size_t)JD * BB;

    hipLaunchKernelGGL(prep_kernel, dim3(18, 8), dim3(256), 0, stream,
                       x, xsh, xsl, xth, xtl, b_ij);
    for (int it = 0; it < 3; ++it) {
        hipLaunchKernelGGL(sgemm_fused, dim3(NJH, NIC), dim3(256), 0, stream,
                           xsh, xsl, W, b_ij, s_part, it == 0 ? 1 : 0);
        hipLaunchKernelGGL(reduce_squash, dim3(BB), dim3(192), 0, stream,
                           s_part, v_out, vth, vtl);
        if (it < 2) {
            hipLaunchKernelGGL(mgemm_agree, dim3(1440), dim3(256), 0, stream,
                               vth, vtl, xth, xtl, W, b_ij);
        }
    }
}